// Round 1
// baseline (206.098 us; speedup 1.0000x reference)
//
#include <hip/hip_runtime.h>

typedef unsigned short US;
typedef __bf16 bf16x8 __attribute__((ext_vector_type(8)));
typedef float f32x4 __attribute__((ext_vector_type(4)));

__device__ __forceinline__ US f2bf(float f) {
  union { float f; unsigned u; } v; v.f = f;
  unsigned r = v.u + 0x7fffu + ((v.u >> 16) & 1u);
  return (US)(r >> 16);
}

// ---------------- kernel 0: pw_w fp32 -> bf16 ----------------
__global__ __launch_bounds__(256) void k_convw(const float* __restrict__ pw,
                                               US* __restrict__ wb) {
  int i = (blockIdx.x * 256 + threadIdx.x) * 4;
  float4 v = *(const float4*)(pw + i);
  ushort4 s;
  s.x = f2bf(v.x); s.y = f2bf(v.y); s.z = f2bf(v.z); s.w = f2bf(v.w);
  *(ushort4*)(wb + i) = s;
}

// ---------------- kernel 1: depthwise 7x7, fp32 -> bf16 y ----------------
// one block per (b, c); LDS tile 70x72 (padded), 256 threads, 16 px/thread
__global__ __launch_bounds__(256) void k_dw(const float* __restrict__ x,
                                            const float* __restrict__ dww,
                                            const float* __restrict__ dwb,
                                            US* __restrict__ y) {
  const int bc = blockIdx.x;          // b*256 + c
  const int c  = bc & 255;
  const float* xp = x + (size_t)bc * 4096;
  __shared__ float tile[70][72];
  const int tid = threadIdx.x;
  for (int i = tid; i < 4900; i += 256) {
    int r  = i / 70;
    int cc = i - r * 70;
    int h = r - 3, w = cc - 3;
    float v = 0.f;
    if ((unsigned)h < 64u && (unsigned)w < 64u) v = xp[h * 64 + w];
    tile[r][cc] = v;
  }
  float wv[49];
  const float* wp = dww + c * 49;   // block-uniform -> SGPR
#pragma unroll
  for (int i = 0; i < 49; ++i) wv[i] = wp[i];
  const float bias = dwb[c];
  __syncthreads();

  const int lane = tid & 63;
  const int wid  = tid >> 6;
  const int w4   = (lane & 15) * 4;
  const int g    = lane >> 4;       // lane groups -> consecutive rows (bank-safe)
  US* yp = y + (size_t)bc * 4096;
#pragma unroll
  for (int ih = 0; ih < 4; ++ih) {
    const int h = wid * 16 + ih * 4 + g;
    float a0 = bias, a1 = bias, a2 = bias, a3 = bias;
#pragma unroll
    for (int kh = 0; kh < 7; ++kh) {
      const float* row = &tile[h + kh][w4];
      float4 p0 = *(const float4*)row;
      float4 p1 = *(const float4*)(row + 4);
      float2 p2 = *(const float2*)(row + 8);
      float rv[10] = {p0.x, p0.y, p0.z, p0.w, p1.x, p1.y, p1.z, p1.w, p2.x, p2.y};
#pragma unroll
      for (int kw = 0; kw < 7; ++kw) {
        const float wk = wv[kh * 7 + kw];
        a0 = fmaf(rv[kw],     wk, a0);
        a1 = fmaf(rv[kw + 1], wk, a1);
        a2 = fmaf(rv[kw + 2], wk, a2);
        a3 = fmaf(rv[kw + 3], wk, a3);
      }
    }
    ushort4 s;
    s.x = f2bf(a0); s.y = f2bf(a1); s.z = f2bf(a2); s.w = f2bf(a3);
    *(ushort4*)(yp + h * 64 + w4) = s;
  }
}

// ---------------- kernel 2: transpose y[b][c][hw] -> yt[b][hw][c] ----------------
__global__ __launch_bounds__(256) void k_tr(const US* __restrict__ y,
                                            US* __restrict__ yt) {
  const int bid = blockIdx.x;
  const int b   = bid >> 8;
  const int rem = bid & 255;
  const int c0  = (rem >> 6) * 64;
  const int hw0 = (rem & 63) * 64;
  __shared__ US lds[64][66];
  const int tid = threadIdx.x;
  const US* yb = y + ((size_t)b * 256 + c0) * 4096 + hw0;
  for (int i = tid; i < 2048; i += 256) {     // uint-granular fill
    int cc  = i >> 5;
    int hh2 = (i & 31) * 2;
    *(unsigned int*)&lds[cc][hh2] = *(const unsigned int*)(yb + (size_t)cc * 4096 + hh2);
  }
  __syncthreads();
  const int lane = tid & 63, wid = tid >> 6;
  US* ytb = yt + ((size_t)b * 4096 + hw0) * 256 + c0;
#pragma unroll
  for (int j = 0; j < 16; ++j) {
    int hh = wid * 16 + j;
    ytb[(size_t)hh * 256 + lane] = lds[lane][hh];
  }
}

// ---------------- kernel 3: pointwise GEMM (MFMA bf16) ----------------
// per batch: out[512][4096] = W(512x256) x Y^T ; tile 128x128, BK=64
__global__ __launch_bounds__(256) void k_pw(const US* __restrict__ yt,
                                            const US* __restrict__ wb,
                                            const float* __restrict__ pwb,
                                            float* __restrict__ out) {
  const int bid = blockIdx.x;
  const int b   = bid >> 7;
  const int mt  = (bid >> 5) & 3;
  const int nt  = bid & 31;
  const int o0  = mt * 128;
  const int hw0 = nt * 128;
  __shared__ US lsA[128][72];
  __shared__ US lsB[128][72];
  const int tid  = threadIdx.x;
  const int lane = tid & 63;
  const int wid  = tid >> 6;
  const int wm   = wid >> 1, wn = wid & 1;
  const US* ytb = yt + (size_t)b * (4096 * 256);

  const f32x4 fzero = {0.f, 0.f, 0.f, 0.f};
  f32x4 acc[4][4];
#pragma unroll
  for (int m = 0; m < 4; ++m)
#pragma unroll
    for (int n = 0; n < 4; ++n) acc[m][n] = fzero;

  const int strow = tid >> 3;   // 0..31
  const int scg   = tid & 7;    // 16B chunk in 128B row

  for (int kt = 0; kt < 4; ++kt) {
    const int ck = kt * 64;
    uint4 ra[4], rb[4];
#pragma unroll
    for (int i = 0; i < 4; ++i) {
      const int row = i * 32 + strow;
      ra[i] = *(const uint4*)(wb  + (size_t)(o0  + row) * 256 + ck + scg * 8);
      rb[i] = *(const uint4*)(ytb + (size_t)(hw0 + row) * 256 + ck + scg * 8);
    }
    __syncthreads();   // previous iteration's compute done with LDS
#pragma unroll
    for (int i = 0; i < 4; ++i) {
      const int row = i * 32 + strow;
      *(uint4*)&lsA[row][scg * 8] = ra[i];
      *(uint4*)&lsB[row][scg * 8] = rb[i];
    }
    __syncthreads();
#pragma unroll
    for (int kk = 0; kk < 2; ++kk) {
      const int kcol = kk * 32 + (lane >> 4) * 8;
      bf16x8 af[4], bfr[4];
#pragma unroll
      for (int m = 0; m < 4; ++m)
        af[m] = *reinterpret_cast<const bf16x8*>(&lsA[wm * 64 + m * 16 + (lane & 15)][kcol]);
#pragma unroll
      for (int n = 0; n < 4; ++n)
        bfr[n] = *reinterpret_cast<const bf16x8*>(&lsB[wn * 64 + n * 16 + (lane & 15)][kcol]);
#pragma unroll
      for (int m = 0; m < 4; ++m)
#pragma unroll
        for (int n = 0; n < 4; ++n)
          acc[m][n] = __builtin_amdgcn_mfma_f32_16x16x32_bf16(af[m], bfr[n], acc[m][n], 0, 0, 0);
    }
  }

  float* ob = out + ((size_t)b * 512 + o0) * 4096 + hw0;
#pragma unroll
  for (int m = 0; m < 4; ++m) {
    const int orow0 = wm * 64 + m * 16 + (lane >> 4) * 4;
#pragma unroll
    for (int r = 0; r < 4; ++r) {
      const int orow = orow0 + r;
      const float bv = pwb[o0 + orow];
#pragma unroll
      for (int n = 0; n < 4; ++n) {
        ob[(size_t)orow * 4096 + wn * 64 + n * 16 + (lane & 15)] = acc[m][n][r] + bv;
      }
    }
  }
}

extern "C" void kernel_launch(void* const* d_in, const int* in_sizes, int n_in,
                              void* d_out, int out_size, void* d_ws, size_t ws_size,
                              hipStream_t stream) {
  const float* x   = (const float*)d_in[0];
  const float* dww = (const float*)d_in[1];
  const float* dwb = (const float*)d_in[2];
  const float* pww = (const float*)d_in[3];
  const float* pwb = (const float*)d_in[4];
  float* out = (float*)d_out;

  char* ws = (char*)d_ws;
  US* y   = (US*)ws;                         // 16*256*4096 bf16 = 33,554,432 B
  US* yt  = (US*)(ws + 33554432);            // same size
  US* wbf = (US*)(ws + 67108864);            // 512*256 bf16 = 262,144 B

  k_convw<<<128,  256, 0, stream>>>(pww, wbf);
  k_dw   <<<4096, 256, 0, stream>>>(x, dww, dwb, y);
  k_tr   <<<4096, 256, 0, stream>>>(y, yt);
  k_pw   <<<2048, 256, 0, stream>>>(yt, wbf, pwb, out);
}

// Round 2
// 140.459 us; speedup vs baseline: 1.4673x; 1.4673x over previous
//
#include <hip/hip_runtime.h>

typedef unsigned short US;
typedef __bf16 bf16x8 __attribute__((ext_vector_type(8)));
typedef float f32x4 __attribute__((ext_vector_type(4)));

__device__ __forceinline__ US f2bf(float f) {
  union { float f; unsigned u; } v; v.f = f;
  unsigned r = v.u + 0x7fffu + ((v.u >> 16) & 1u);
  return (US)(r >> 16);
}

// ---------------- kernel 0: pw_w fp32 -> bf16 ----------------
__global__ __launch_bounds__(256) void k_convw(const float* __restrict__ pw,
                                               US* __restrict__ wb) {
  int i = (blockIdx.x * 256 + threadIdx.x) * 4;
  float4 v = *(const float4*)(pw + i);
  ushort4 s;
  s.x = f2bf(v.x); s.y = f2bf(v.y); s.z = f2bf(v.z); s.w = f2bf(v.w);
  *(ushort4*)(wb + i) = s;
}

// ---------------- kernel 1: depthwise 7x7, fp32 -> bf16 y ----------------
// one block per (b, c); LDS tile 70x72 (padded), 256 threads, 16 px/thread
__global__ __launch_bounds__(256) void k_dw(const float* __restrict__ x,
                                            const float* __restrict__ dww,
                                            const float* __restrict__ dwb,
                                            US* __restrict__ y) {
  const int bc = blockIdx.x;          // b*256 + c
  const int c  = bc & 255;
  const float* xp = x + (size_t)bc * 4096;
  __shared__ float tile[70][72];
  const int tid  = threadIdx.x;
  const int lane = tid & 63;
  const int wid  = tid >> 6;
  // fill without integer division: wave w handles rows w, w+4, ...
  for (int r = wid; r < 70; r += 4) {
    const int h = r - 3;
    const int w = lane - 3;
    float v = 0.f;
    if ((unsigned)h < 64u && (unsigned)w < 64u) v = xp[h * 64 + w];
    tile[r][lane] = v;
    if (lane < 6) {
      const int w2 = lane + 61;
      float v2 = ((unsigned)h < 64u && w2 < 64) ? xp[h * 64 + w2] : 0.f;
      tile[r][lane + 64] = v2;
    }
  }
  float wv[49];
  const float* wp = dww + c * 49;   // block-uniform
#pragma unroll
  for (int i = 0; i < 49; ++i) wv[i] = wp[i];
  const float bias = dwb[c];
  __syncthreads();

  const int w4 = (lane & 15) * 4;
  const int g  = lane >> 4;         // lane groups -> consecutive rows (bank-safe)
  US* yp = y + (size_t)bc * 4096;
#pragma unroll
  for (int ih = 0; ih < 4; ++ih) {
    const int h = wid * 16 + ih * 4 + g;
    float a0 = bias, a1 = bias, a2 = bias, a3 = bias;
#pragma unroll
    for (int kh = 0; kh < 7; ++kh) {
      const float* row = &tile[h + kh][w4];
      float4 p0 = *(const float4*)row;
      float4 p1 = *(const float4*)(row + 4);
      float2 p2 = *(const float2*)(row + 8);
      float rv[10] = {p0.x, p0.y, p0.z, p0.w, p1.x, p1.y, p1.z, p1.w, p2.x, p2.y};
#pragma unroll
      for (int kw = 0; kw < 7; ++kw) {
        const float wk = wv[kh * 7 + kw];
        a0 = fmaf(rv[kw],     wk, a0);
        a1 = fmaf(rv[kw + 1], wk, a1);
        a2 = fmaf(rv[kw + 2], wk, a2);
        a3 = fmaf(rv[kw + 3], wk, a3);
      }
    }
    ushort4 s;
    s.x = f2bf(a0); s.y = f2bf(a1); s.z = f2bf(a2); s.w = f2bf(a3);
    *(ushort4*)(yp + h * 64 + w4) = s;
  }
}

// ---------------- kernel 2: transpose y[b][c][hw] -> yt[b][hw][c] ----------------
__global__ __launch_bounds__(256) void k_tr(const US* __restrict__ y,
                                            US* __restrict__ yt) {
  const int bid = blockIdx.x;
  const int b   = bid >> 8;
  const int rem = bid & 255;
  const int c0  = (rem >> 6) * 64;
  const int hw0 = (rem & 63) * 64;
  __shared__ US lds[64][66];
  const int tid = threadIdx.x;
  const US* yb = y + ((size_t)b * 256 + c0) * 4096 + hw0;
  for (int i = tid; i < 2048; i += 256) {     // uint-granular fill
    int cc  = i >> 5;
    int hh2 = (i & 31) * 2;
    *(unsigned int*)&lds[cc][hh2] = *(const unsigned int*)(yb + (size_t)cc * 4096 + hh2);
  }
  __syncthreads();
  const int lane = tid & 63, wid = tid >> 6;
  US* ytb = yt + ((size_t)b * 4096 + hw0) * 256 + c0;
#pragma unroll
  for (int j = 0; j < 16; ++j) {
    int hh = wid * 16 + j;
    ytb[(size_t)hh * 256 + lane] = lds[lane][hh];
  }
}

// ---------------- kernel 3: pointwise GEMM (MFMA bf16), v2 ----------------
// out^T fragments via swapped operands; double-buffered LDS; XCD swizzle.
// per batch: out[512][4096] = W(512x256) x Y^T ; tile 128o x 128px, BK=64
__global__ __launch_bounds__(256, 2) void k_pw(const US* __restrict__ yt,
                                               const US* __restrict__ wb,
                                               const float* __restrict__ pwb,
                                               float* __restrict__ out) {
  // bijective XCD swizzle (nwg=2048, %8==0): chunk of 256 per XCD
  const int bid = blockIdx.x;
  const int s   = ((bid & 7) << 8) | (bid >> 3);
  const int b   = s >> 7;
  const int rr  = s & 127;
  const int nt  = rr >> 2;        // px tile (32)
  const int mt  = rr & 3;         // o tile (4) innermost -> yt-tile L2 reuse
  const int o0  = mt * 128;
  const int hw0 = nt * 128;

  __shared__ US lsA[2][128][72];
  __shared__ US lsB[2][128][72];
  const int tid  = threadIdx.x;
  const int lane = tid & 63;
  const int wid  = tid >> 6;
  const int wm   = wid >> 1, wn = wid & 1;
  const US* ytb  = yt + (size_t)b * (4096 * 256);
  const int strow = tid >> 3;     // 0..31
  const int scg   = tid & 7;      // 16B chunk within 128B k-row

  const f32x4 fzero = {0.f, 0.f, 0.f, 0.f};
  f32x4 acc[4][4];
#pragma unroll
  for (int m = 0; m < 4; ++m)
#pragma unroll
    for (int n = 0; n < 4; ++n) acc[m][n] = fzero;

  uint4 ra[4], rb[4];
  // prologue: stage kt=0 into buffer 0
#pragma unroll
  for (int i = 0; i < 4; ++i) {
    const int row = i * 32 + strow;
    ra[i] = *(const uint4*)(wb  + (size_t)(o0  + row) * 256 + scg * 8);
    rb[i] = *(const uint4*)(ytb + (size_t)(hw0 + row) * 256 + scg * 8);
  }
#pragma unroll
  for (int i = 0; i < 4; ++i) {
    const int row = i * 32 + strow;
    *(uint4*)&lsA[0][row][scg * 8] = ra[i];
    *(uint4*)&lsB[0][row][scg * 8] = rb[i];
  }
  __syncthreads();

  for (int kt = 0; kt < 4; ++kt) {
    const int cur = kt & 1;
    // issue-early: global loads for next tile (hide under compute)
    if (kt < 3) {
      const int ck = (kt + 1) * 64;
#pragma unroll
      for (int i = 0; i < 4; ++i) {
        const int row = i * 32 + strow;
        ra[i] = *(const uint4*)(wb  + (size_t)(o0  + row) * 256 + ck + scg * 8);
        rb[i] = *(const uint4*)(ytb + (size_t)(hw0 + row) * 256 + ck + scg * 8);
      }
    }
    bf16x8 af[2][4], bfr[2][4];
#pragma unroll
    for (int kk = 0; kk < 2; ++kk) {
      const int kcol = kk * 32 + (lane >> 4) * 8;
#pragma unroll
      for (int m = 0; m < 4; ++m)
        af[kk][m] = *reinterpret_cast<const bf16x8*>(&lsA[cur][wm * 64 + m * 16 + (lane & 15)][kcol]);
#pragma unroll
      for (int n = 0; n < 4; ++n)
        bfr[kk][n] = *reinterpret_cast<const bf16x8*>(&lsB[cur][wn * 64 + n * 16 + (lane & 15)][kcol]);
    }
#pragma unroll
    for (int kk = 0; kk < 2; ++kk)
#pragma unroll
      for (int m = 0; m < 4; ++m)
#pragma unroll
        for (int n = 0; n < 4; ++n)
          // swapped operands: acc = (Y^T)*(W^T) = out^T fragment
          acc[m][n] = __builtin_amdgcn_mfma_f32_16x16x32_bf16(bfr[kk][n], af[kk][m], acc[m][n], 0, 0, 0);

    if (kt < 3) {
#pragma unroll
      for (int i = 0; i < 4; ++i) {
        const int row = i * 32 + strow;
        *(uint4*)&lsA[cur ^ 1][row][scg * 8] = ra[i];
        *(uint4*)&lsB[cur ^ 1][row][scg * 8] = rb[i];
      }
      __syncthreads();
    }
  }

  // epilogue: D^T layout -> lane holds 4 consecutive px at fixed o: dwordx4 stores
#pragma unroll
  for (int m = 0; m < 4; ++m) {
    const int o  = o0 + wm * 64 + m * 16 + (lane & 15);
    const float bv = pwb[o];
    float* orow = out + (((size_t)b * 512 + o) * 4096) + hw0 + wn * 64 + (lane >> 4) * 4;
#pragma unroll
    for (int n = 0; n < 4; ++n) {
      f32x4 v = acc[m][n];
      v[0] += bv; v[1] += bv; v[2] += bv; v[3] += bv;
      *(f32x4*)(orow + n * 16) = v;
    }
  }
}

extern "C" void kernel_launch(void* const* d_in, const int* in_sizes, int n_in,
                              void* d_out, int out_size, void* d_ws, size_t ws_size,
                              hipStream_t stream) {
  const float* x   = (const float*)d_in[0];
  const float* dww = (const float*)d_in[1];
  const float* dwb = (const float*)d_in[2];
  const float* pww = (const float*)d_in[3];
  const float* pwb = (const float*)d_in[4];
  float* out = (float*)d_out;

  char* ws = (char*)d_ws;
  US* y   = (US*)ws;                         // 16*256*4096 bf16 = 33,554,432 B
  US* yt  = (US*)(ws + 33554432);            // same size
  US* wbf = (US*)(ws + 67108864);            // 512*256 bf16 = 262,144 B

  k_convw<<<128,  256, 0, stream>>>(pww, wbf);
  k_dw   <<<4096, 256, 0, stream>>>(x, dww, dwb, y);
  k_tr   <<<4096, 256, 0, stream>>>(y, yt);
  k_pw   <<<2048, 256, 0, stream>>>(yt, wbf, pwb, out);
}

// Round 3
// 96.669 us; speedup vs baseline: 2.1320x; 1.4530x over previous
//
#include <hip/hip_runtime.h>

typedef unsigned short US;
typedef __bf16 bf16x8 __attribute__((ext_vector_type(8)));
typedef float f32x4 __attribute__((ext_vector_type(4)));

__device__ __forceinline__ US f2bf(float f) {
  union { float f; unsigned u; } v; v.f = f;
  unsigned r = v.u + 0x7fffu + ((v.u >> 16) & 1u);
  return (US)(r >> 16);
}

// ---------------- kernel 0: pw_w fp32 -> bf16 ----------------
__global__ __launch_bounds__(256) void k_convw(const float* __restrict__ pw,
                                               US* __restrict__ wb) {
  int i = (blockIdx.x * 256 + threadIdx.x) * 4;
  float4 v = *(const float4*)(pw + i);
  ushort4 s;
  s.x = f2bf(v.x); s.y = f2bf(v.y); s.z = f2bf(v.z); s.w = f2bf(v.w);
  *(ushort4*)(wb + i) = s;
}

// ---------------- kernel 1: depthwise 7x7, register sliding window ----------------
// one block per (b,c); thread computes a 4x4 px block; 10 input rows read once
// each as 3 aligned float4 straight from global (plane is L1/L2 resident).
// No LDS, no barriers, no bank conflicts.
__global__ __launch_bounds__(256) void k_dw(const float* __restrict__ x,
                                            const float* __restrict__ dww,
                                            const float* __restrict__ dwb,
                                            US* __restrict__ y) {
  const int bc  = blockIdx.x;          // b*256 + c
  const int cch = bc & 255;
  const float* xp = x + (size_t)bc * 4096;
  float wv[49];
  const float* wp = dww + cch * 49;    // block-uniform -> s_load
#pragma unroll
  for (int i = 0; i < 49; ++i) wv[i] = wp[i];
  const float bias = dwb[cch];

  const int t   = threadIdx.x;
  const int br  = (t >> 4) * 4;        // output row base 0..60
  const int bcx = (t & 15) * 4;        // output col base 0..60

  float acc[4][4];
#pragma unroll
  for (int o = 0; o < 4; ++o)
#pragma unroll
    for (int q = 0; q < 4; ++q) acc[o][q] = bias;

#pragma unroll
  for (int j = 0; j < 10; ++j) {
    const int r = br - 3 + j;          // input row
    float L[12];                       // cols bcx-4 .. bcx+7
    if ((unsigned)r < 64u) {
      const float* rp = xp + r * 64 + bcx;
      float4 a = (bcx >= 4)  ? *(const float4*)(rp - 4) : float4{0.f,0.f,0.f,0.f};
      float4 b = *(const float4*)(rp);
      float4 c = (bcx < 60)  ? *(const float4*)(rp + 4) : float4{0.f,0.f,0.f,0.f};
      L[0]=a.x; L[1]=a.y; L[2]=a.z;  L[3]=a.w;
      L[4]=b.x; L[5]=b.y; L[6]=b.z;  L[7]=b.w;
      L[8]=c.x; L[9]=c.y; L[10]=c.z; L[11]=c.w;
    } else {
#pragma unroll
      for (int i2 = 0; i2 < 12; ++i2) L[i2] = 0.f;
    }
#pragma unroll
    for (int o = 0; o < 4; ++o) {
      if (j - o >= 0 && j - o <= 6) {  // compile-time after unroll
        const int kh = j - o;
#pragma unroll
        for (int kw = 0; kw < 7; ++kw) {
          const float wk = wv[kh * 7 + kw];
#pragma unroll
          for (int q = 0; q < 4; ++q)
            acc[o][q] = fmaf(L[q + kw + 1], wk, acc[o][q]);
        }
      }
    }
  }

  US* yp = y + (size_t)bc * 4096;
#pragma unroll
  for (int o = 0; o < 4; ++o) {
    ushort4 s;
    s.x = f2bf(acc[o][0]); s.y = f2bf(acc[o][1]);
    s.z = f2bf(acc[o][2]); s.w = f2bf(acc[o][3]);
    *(ushort4*)(yp + (br + o) * 64 + bcx) = s;
  }
}

// ---------------- kernel 2: transpose y[b][c][hw] -> yt[b][hw][c] ----------------
__global__ __launch_bounds__(256) void k_tr(const US* __restrict__ y,
                                            US* __restrict__ yt) {
  const int bid = blockIdx.x;
  const int b   = bid >> 8;
  const int rem = bid & 255;
  const int c0  = (rem >> 6) * 64;
  const int hw0 = (rem & 63) * 64;
  __shared__ US lds[64][66];
  const int tid = threadIdx.x;
  const US* yb = y + ((size_t)b * 256 + c0) * 4096 + hw0;
  for (int i = tid; i < 2048; i += 256) {     // uint-granular fill
    int cc  = i >> 5;
    int hh2 = (i & 31) * 2;
    *(unsigned int*)&lds[cc][hh2] = *(const unsigned int*)(yb + (size_t)cc * 4096 + hh2);
  }
  __syncthreads();
  const int lane = tid & 63, wid = tid >> 6;
  US* ytb = yt + ((size_t)b * 4096 + hw0) * 256 + c0;
#pragma unroll
  for (int j = 0; j < 16; ++j) {
    int hh = wid * 16 + j;
    ytb[(size_t)hh * 256 + lane] = lds[lane][hh];
  }
}

// ---------------- kernel 3: pointwise GEMM (MFMA bf16) ----------------
// out^T fragments via swapped operands; double-buffered LDS; XCD swizzle.
// per batch: out[512][4096] = W(512x256) x Y^T ; tile 128o x 128px, BK=64
__global__ __launch_bounds__(256, 2) void k_pw(const US* __restrict__ yt,
                                               const US* __restrict__ wb,
                                               const float* __restrict__ pwb,
                                               float* __restrict__ out) {
  // bijective XCD swizzle (nwg=2048, %8==0): chunk of 256 per XCD
  const int bid = blockIdx.x;
  const int s   = ((bid & 7) << 8) | (bid >> 3);
  const int b   = s >> 7;
  const int rr  = s & 127;
  const int nt  = rr >> 2;        // px tile (32)
  const int mt  = rr & 3;         // o tile (4) innermost -> yt-tile L2 reuse
  const int o0  = mt * 128;
  const int hw0 = nt * 128;

  __shared__ US lsA[2][128][72];
  __shared__ US lsB[2][128][72];
  const int tid  = threadIdx.x;
  const int lane = tid & 63;
  const int wid  = tid >> 6;
  const int wm   = wid >> 1, wn = wid & 1;
  const US* ytb  = yt + (size_t)b * (4096 * 256);
  const int strow = tid >> 3;     // 0..31
  const int scg   = tid & 7;      // 16B chunk within 128B k-row

  const f32x4 fzero = {0.f, 0.f, 0.f, 0.f};
  f32x4 acc[4][4];
#pragma unroll
  for (int m = 0; m < 4; ++m)
#pragma unroll
    for (int n = 0; n < 4; ++n) acc[m][n] = fzero;

  uint4 ra[4], rb[4];
  // prologue: stage kt=0 into buffer 0
#pragma unroll
  for (int i = 0; i < 4; ++i) {
    const int row = i * 32 + strow;
    ra[i] = *(const uint4*)(wb  + (size_t)(o0  + row) * 256 + scg * 8);
    rb[i] = *(const uint4*)(ytb + (size_t)(hw0 + row) * 256 + scg * 8);
  }
#pragma unroll
  for (int i = 0; i < 4; ++i) {
    const int row = i * 32 + strow;
    *(uint4*)&lsA[0][row][scg * 8] = ra[i];
    *(uint4*)&lsB[0][row][scg * 8] = rb[i];
  }
  __syncthreads();

  for (int kt = 0; kt < 4; ++kt) {
    const int cur = kt & 1;
    // issue-early: global loads for next tile (hide under compute)
    if (kt < 3) {
      const int ck = (kt + 1) * 64;
#pragma unroll
      for (int i = 0; i < 4; ++i) {
        const int row = i * 32 + strow;
        ra[i] = *(const uint4*)(wb  + (size_t)(o0  + row) * 256 + ck + scg * 8);
        rb[i] = *(const uint4*)(ytb + (size_t)(hw0 + row) * 256 + ck + scg * 8);
      }
    }
    bf16x8 af[2][4], bfr[2][4];
#pragma unroll
    for (int kk = 0; kk < 2; ++kk) {
      const int kcol = kk * 32 + (lane >> 4) * 8;
#pragma unroll
      for (int m = 0; m < 4; ++m)
        af[kk][m] = *reinterpret_cast<const bf16x8*>(&lsA[cur][wm * 64 + m * 16 + (lane & 15)][kcol]);
#pragma unroll
      for (int n = 0; n < 4; ++n)
        bfr[kk][n] = *reinterpret_cast<const bf16x8*>(&lsB[cur][wn * 64 + n * 16 + (lane & 15)][kcol]);
    }
#pragma unroll
    for (int kk = 0; kk < 2; ++kk)
#pragma unroll
      for (int m = 0; m < 4; ++m)
#pragma unroll
        for (int n = 0; n < 4; ++n)
          // swapped operands: acc = (Y^T)*(W^T) = out^T fragment
          acc[m][n] = __builtin_amdgcn_mfma_f32_16x16x32_bf16(bfr[kk][n], af[kk][m], acc[m][n], 0, 0, 0);

    if (kt < 3) {
#pragma unroll
      for (int i = 0; i < 4; ++i) {
        const int row = i * 32 + strow;
        *(uint4*)&lsA[cur ^ 1][row][scg * 8] = ra[i];
        *(uint4*)&lsB[cur ^ 1][row][scg * 8] = rb[i];
      }
      __syncthreads();
    }
  }

  // epilogue: D^T layout -> lane holds 4 consecutive px at fixed o: dwordx4 stores
#pragma unroll
  for (int m = 0; m < 4; ++m) {
    const int o  = o0 + wm * 64 + m * 16 + (lane & 15);
    const float bv = pwb[o];
    float* orow = out + (((size_t)b * 512 + o) * 4096) + hw0 + wn * 64 + (lane >> 4) * 4;
#pragma unroll
    for (int n = 0; n < 4; ++n) {
      f32x4 v = acc[m][n];
      v[0] += bv; v[1] += bv; v[2] += bv; v[3] += bv;
      *(f32x4*)(orow + n * 16) = v;
    }
  }
}

extern "C" void kernel_launch(void* const* d_in, const int* in_sizes, int n_in,
                              void* d_out, int out_size, void* d_ws, size_t ws_size,
                              hipStream_t stream) {
  const float* x   = (const float*)d_in[0];
  const float* dww = (const float*)d_in[1];
  const float* dwb = (const float*)d_in[2];
  const float* pww = (const float*)d_in[3];
  const float* pwb = (const float*)d_in[4];
  float* out = (float*)d_out;

  char* ws = (char*)d_ws;
  US* y   = (US*)ws;                         // 16*256*4096 bf16 = 33,554,432 B
  US* yt  = (US*)(ws + 33554432);            // same size
  US* wbf = (US*)(ws + 67108864);            // 512*256 bf16 = 262,144 B

  k_convw<<<128,  256, 0, stream>>>(pww, wbf);
  k_dw   <<<4096, 256, 0, stream>>>(x, dww, dwb, y);
  k_tr   <<<4096, 256, 0, stream>>>(y, yt);
  k_pw   <<<2048, 256, 0, stream>>>(yt, wbf, pwb, out);
}

// Round 4
// 87.992 us; speedup vs baseline: 2.3422x; 1.0986x over previous
//
#include <hip/hip_runtime.h>

typedef unsigned short US;
typedef __bf16 bf16x8 __attribute__((ext_vector_type(8)));
typedef float f32x4 __attribute__((ext_vector_type(4)));

__device__ __forceinline__ US f2bf(float f) {
  union { float f; unsigned u; } v; v.f = f;
  unsigned r = v.u + 0x7fffu + ((v.u >> 16) & 1u);
  return (US)(r >> 16);
}

// ---------------- kernel 0: pw_w fp32 -> bf16 ----------------
__global__ __launch_bounds__(256) void k_convw(const float* __restrict__ pw,
                                               US* __restrict__ wb) {
  int i = (blockIdx.x * 256 + threadIdx.x) * 4;
  float4 v = *(const float4*)(pw + i);
  ushort4 s;
  s.x = f2bf(v.x); s.y = f2bf(v.y); s.z = f2bf(v.z); s.w = f2bf(v.w);
  *(ushort4*)(wb + i) = s;
}

// ---------------- kernel 1: depthwise 7x7 -> y8 [b][c/8][px][8c] ----------------
// 512 threads = 8 channels (one per wave) x 16 rows x 64 cols; register
// sliding window from global (L1/L2 resident); LDS transpose epilogue packs
// 8 channels into 16B units so the GEMM B-operand is a contiguous uint4.
__global__ __launch_bounds__(512, 4) void k_dw(const float* __restrict__ x,
                                               const float* __restrict__ dww,
                                               const float* __restrict__ dwb,
                                               US* __restrict__ y8) {
  const int bid = blockIdx.x;           // b(16) * cg(32) * rg(4)
  const int rg  = bid & 3;
  const int cg  = (bid >> 2) & 31;
  const int b   = bid >> 7;
  const int t   = threadIdx.x;
  const int w   = t >> 6;               // wave id = channel slot 0..7
  const int l   = t & 63;
  const int g   = l >> 4;               // row quad 0..3
  const int cb  = l & 15;               // col quad 0..15
  const int c   = __builtin_amdgcn_readfirstlane(cg * 8 + w);  // wave-uniform
  const float* xp = x + ((size_t)b * 256 + c) * 4096;
  float wv[49];
  const float* wp = dww + c * 49;       // scalar base -> s_load
#pragma unroll
  for (int i = 0; i < 49; ++i) wv[i] = wp[i];
  const float bias = dwb[c];

  const int r0  = rg * 16;
  const int br  = r0 + g * 4;           // this thread's output row base
  const int bcx = cb * 4;               // this thread's output col base

  float acc[4][4];
#pragma unroll
  for (int o = 0; o < 4; ++o)
#pragma unroll
    for (int q = 0; q < 4; ++q) acc[o][q] = bias;

#pragma unroll
  for (int j = 0; j < 10; ++j) {
    const int r = br - 3 + j;           // input row
    float L[12];                        // cols bcx-4 .. bcx+7
    if ((unsigned)r < 64u) {
      const float* rp = xp + r * 64 + bcx;
      float4 a = (bcx >= 4) ? *(const float4*)(rp - 4) : float4{0.f, 0.f, 0.f, 0.f};
      float4 bb = *(const float4*)(rp);
      float4 cc = (bcx < 60) ? *(const float4*)(rp + 4) : float4{0.f, 0.f, 0.f, 0.f};
      L[0]=a.x; L[1]=a.y; L[2]=a.z;  L[3]=a.w;
      L[4]=bb.x; L[5]=bb.y; L[6]=bb.z; L[7]=bb.w;
      L[8]=cc.x; L[9]=cc.y; L[10]=cc.z; L[11]=cc.w;
    } else {
#pragma unroll
      for (int i2 = 0; i2 < 12; ++i2) L[i2] = 0.f;
    }
#pragma unroll
    for (int o = 0; o < 4; ++o) {
      if (j - o >= 0 && j - o <= 6) {   // compile-time after unroll
        const int kh = j - o;
#pragma unroll
        for (int kw = 0; kw < 7; ++kw) {
          const float wk = wv[kh * 7 + kw];
#pragma unroll
          for (int q = 0; q < 4; ++q)
            acc[o][q] = fmaf(L[q + kw + 1], wk, acc[o][q]);
        }
      }
    }
  }

  // LDS transpose: [8c][1024 px], then pack px-pairs into y8 uint4s
  __shared__ US t8[8][1024];
#pragma unroll
  for (int o = 0; o < 4; ++o) {
    ushort4 s;
    s.x = f2bf(acc[o][0]); s.y = f2bf(acc[o][1]);
    s.z = f2bf(acc[o][2]); s.w = f2bf(acc[o][3]);
    *(ushort4*)&t8[w][(g * 4 + o) * 64 + bcx] = s;
  }
  __syncthreads();

  unsigned rc[8];
#pragma unroll
  for (int c2 = 0; c2 < 8; ++c2) rc[c2] = *(const unsigned*)&t8[c2][2 * t];
  uint4 A, B2;
  A.x  = __builtin_amdgcn_perm(rc[1], rc[0], 0x05040100u);  // px even: c0,c1
  A.y  = __builtin_amdgcn_perm(rc[3], rc[2], 0x05040100u);
  A.z  = __builtin_amdgcn_perm(rc[5], rc[4], 0x05040100u);
  A.w  = __builtin_amdgcn_perm(rc[7], rc[6], 0x05040100u);
  B2.x = __builtin_amdgcn_perm(rc[1], rc[0], 0x07060302u);  // px odd
  B2.y = __builtin_amdgcn_perm(rc[3], rc[2], 0x07060302u);
  B2.z = __builtin_amdgcn_perm(rc[5], rc[4], 0x07060302u);
  B2.w = __builtin_amdgcn_perm(rc[7], rc[6], 0x07060302u);
  US* yb = y8 + (((size_t)b * 32 + cg) * 4096 + r0 * 64) * 8 + (size_t)t * 16;
  *(uint4*)(yb)     = A;
  *(uint4*)(yb + 8) = B2;
}

// ---------------- kernel 2: pointwise GEMM (MFMA bf16) ----------------
// out^T fragments via swapped operands; double-buffered LDS; XCD swizzle.
// per batch: out[512][4096] = W(512x256) x Y^T ; tile 128o x 128px, BK=64
// B staged directly from y8 (16B/px/8c units) -> identical LDS layout.
__global__ __launch_bounds__(256, 2) void k_pw(const US* __restrict__ y8,
                                               const US* __restrict__ wb,
                                               const float* __restrict__ pwb,
                                               float* __restrict__ out) {
  // bijective XCD swizzle (nwg=2048, %8==0): chunk of 256 per XCD
  const int bid = blockIdx.x;
  const int s   = ((bid & 7) << 8) | (bid >> 3);
  const int b   = s >> 7;
  const int rr  = s & 127;
  const int nt  = rr >> 2;        // px tile (32)
  const int mt  = rr & 3;         // o tile (4) innermost -> y8-tile L2 reuse
  const int o0  = mt * 128;
  const int hw0 = nt * 128;

  __shared__ US lsA[2][128][72];
  __shared__ US lsB[2][128][72];
  const int tid  = threadIdx.x;
  const int lane = tid & 63;
  const int wid  = tid >> 6;
  const int wm   = wid >> 1, wn = wid & 1;
  const int strow = tid >> 3;     // A-stage: 0..31
  const int scg   = tid & 7;      // A-stage: 16B chunk within 128B k-row
  const int bg    = tid >> 5;     // B-stage: 8c-group 0..7
  const int bl    = tid & 31;     // B-stage: px within group of 32

  const f32x4 fzero = {0.f, 0.f, 0.f, 0.f};
  f32x4 acc[4][4];
#pragma unroll
  for (int m = 0; m < 4; ++m)
#pragma unroll
    for (int n = 0; n < 4; ++n) acc[m][n] = fzero;

  uint4 ra[4], rb[4];
  // prologue: stage kt=0 into buffer 0
#pragma unroll
  for (int i = 0; i < 4; ++i) {
    ra[i] = *(const uint4*)(wb + (size_t)(o0 + i * 32 + strow) * 256 + scg * 8);
    rb[i] = *(const uint4*)(y8 + ((size_t)(b * 32 + bg) * 4096 + hw0 + bl + 32 * i) * 8);
  }
#pragma unroll
  for (int i = 0; i < 4; ++i) {
    *(uint4*)&lsA[0][i * 32 + strow][scg * 8] = ra[i];
    *(uint4*)&lsB[0][bl + 32 * i][bg * 8]     = rb[i];
  }
  __syncthreads();

  for (int kt = 0; kt < 4; ++kt) {
    const int cur = kt & 1;
    // issue-early: global loads for next tile (hide under compute)
    if (kt < 3) {
      const int ck = (kt + 1) * 64;
#pragma unroll
      for (int i = 0; i < 4; ++i) {
        ra[i] = *(const uint4*)(wb + (size_t)(o0 + i * 32 + strow) * 256 + ck + scg * 8);
        rb[i] = *(const uint4*)(y8 + ((size_t)(b * 32 + (ck >> 3) + bg) * 4096 + hw0 + bl + 32 * i) * 8);
      }
    }
    bf16x8 af[2][4], bfr[2][4];
#pragma unroll
    for (int kk = 0; kk < 2; ++kk) {
      const int kcol = kk * 32 + (lane >> 4) * 8;
#pragma unroll
      for (int m = 0; m < 4; ++m)
        af[kk][m] = *reinterpret_cast<const bf16x8*>(&lsA[cur][wm * 64 + m * 16 + (lane & 15)][kcol]);
#pragma unroll
      for (int n = 0; n < 4; ++n)
        bfr[kk][n] = *reinterpret_cast<const bf16x8*>(&lsB[cur][wn * 64 + n * 16 + (lane & 15)][kcol]);
    }
#pragma unroll
    for (int kk = 0; kk < 2; ++kk)
#pragma unroll
      for (int m = 0; m < 4; ++m)
#pragma unroll
        for (int n = 0; n < 4; ++n)
          // swapped operands: acc = (Y^T)*(W^T) = out^T fragment
          acc[m][n] = __builtin_amdgcn_mfma_f32_16x16x32_bf16(bfr[kk][n], af[kk][m], acc[m][n], 0, 0, 0);

    if (kt < 3) {
#pragma unroll
      for (int i = 0; i < 4; ++i) {
        *(uint4*)&lsA[cur ^ 1][i * 32 + strow][scg * 8] = ra[i];
        *(uint4*)&lsB[cur ^ 1][bl + 32 * i][bg * 8]     = rb[i];
      }
      __syncthreads();
    }
  }

  // epilogue: D^T layout -> lane holds 4 consecutive px at fixed o: dwordx4 stores
#pragma unroll
  for (int m = 0; m < 4; ++m) {
    const int o  = o0 + wm * 64 + m * 16 + (lane & 15);
    const float bv = pwb[o];
    float* orow = out + (((size_t)b * 512 + o) * 4096) + hw0 + wn * 64 + (lane >> 4) * 4;
#pragma unroll
    for (int n = 0; n < 4; ++n) {
      f32x4 v = acc[m][n];
      v[0] += bv; v[1] += bv; v[2] += bv; v[3] += bv;
      *(f32x4*)(orow + n * 16) = v;
    }
  }
}

extern "C" void kernel_launch(void* const* d_in, const int* in_sizes, int n_in,
                              void* d_out, int out_size, void* d_ws, size_t ws_size,
                              hipStream_t stream) {
  const float* x   = (const float*)d_in[0];
  const float* dww = (const float*)d_in[1];
  const float* dwb = (const float*)d_in[2];
  const float* pww = (const float*)d_in[3];
  const float* pwb = (const float*)d_in[4];
  float* out = (float*)d_out;

  char* ws = (char*)d_ws;
  US* y8  = (US*)ws;                         // 16*32*4096*8 bf16 = 33,554,432 B
  US* wbf = (US*)(ws + 33554432);            // 512*256 bf16 = 262,144 B

  k_convw<<<128,  256, 0, stream>>>(pww, wbf);
  k_dw   <<<2048, 512, 0, stream>>>(x, dww, dwb, y8);
  k_pw   <<<2048, 256, 0, stream>>>(y8, wbf, pwb, out);
}